// Round 5
// baseline (1278.906 us; speedup 1.0000x reference)
//
#include <hip/hip_runtime.h>
#include <hip/hip_bf16.h>
#include <stdint.h>

#define NROWS 131072
#define EPSBN 1e-5f
#define LEAKK 0.33f
#define NBLK  512            // 2 blocks/CU (72KB LDS, VGPR<=256): co-resident

typedef __bf16 bf16x8_t __attribute__((ext_vector_type(8)));
typedef float  f32x4_t  __attribute__((ext_vector_type(4)));

__device__ __forceinline__ float leaky_f(float x) { return fmaxf(x, LEAKK * x); }

#define GLDS16(g, l)                                                          \
    __builtin_amdgcn_global_load_lds(                                         \
        (const __attribute__((address_space(1))) void*)(g),                   \
        (__attribute__((address_space(3))) void*)(l), 16, 0, 0)

#define CFENCE() asm volatile("" ::: "memory")

// Fused gather-GEMM conv + BN(+leaky)(+residual), grid-wide spin sync.
// Conv body = r1's proven-clean depth-1 reg-gather loop (37us/conv, no
// spill). r3/r4 lesson: depth-2 A prefetch (96 A-VGPRs) trips hipcc's
// allocator into a VGPR=108 scratch fallback REGARDLESS of indexing style;
// depth-1 (64 A-VGPRs, peak ~190 live) compiles clean. Fusion (proven
// correct in r4: passed, absmax 0.09375) deletes bnact/resid dispatches.
// mode: 0 = y=leaky(bn(acc))          -> dst bf16   (conv1)
//       1 = y=leaky(bn(acc)+residh)   -> dst bf16   (conv2, b=1,2)
//       2 = y=leaky(bn(acc)+residf)   -> dst bf16   (conv2, b=0, fp32 resid)
//       3 = y=leaky(bn(acc)+residh)   -> dout fp32  (conv2, b=3, final)
__global__ __launch_bounds__(256, 2) void conv_kernel(
    const __bf16* __restrict__ src,      // (NROWS+1) x 64, row NROWS = zeros
    const int* __restrict__ cidxT,       // [9][NROWS] premasked (masked->NROWS)
    const __bf16* __restrict__ wt,       // [9][64 d][64 c]
    __bf16* dst,                         // no restrict: may alias residh
    float* __restrict__ stat,            // 128 sums + counter at [128]
    const float* __restrict__ gamma, const float* __restrict__ beta,
    const __bf16* residh, const float* residf,
    float* dout, int mode)
{
    __shared__ char Bw[9][8192];         // 72KB

    const int tid  = threadIdx.x;
    const int lane = tid & 63;
    const int wv   = tid >> 6;                 // 0..3
    const int quad = lane >> 4;
    const int l15  = lane & 15;
    const int row0 = blockIdx.x << 8;          // 256 rows/block
    const int srow = tid >> 3;                 // staging row 0..31
    const int cg   = (tid & 7) ^ (srow & 7);   // swizzled global chunk
    const int ldsl = (tid & 192) << 4;         // wave-uniform lds base
    const int sxor = l15 & 7;

    const char* srcb = (const char*)src;
    const char* wtb  = (const char*)wt;

    f32x4_t acc[4][4];
#pragma unroll
    for (int mt = 0; mt < 4; ++mt)
#pragma unroll
        for (int nt = 0; nt < 4; ++nt)
            acc[mt][nt] = (f32x4_t){0.f, 0.f, 0.f, 0.f};

    const int ibase = row0 + (wv << 6) + l15;  // wave row, + mt*16 per mt
    const unsigned qofs = (unsigned)(quad << 4);

    // ---- prologue (r1 verbatim): idx k=0,1 then all 9 B tiles ----
    int ixv[2][4];
#pragma unroll
    for (int mt = 0; mt < 4; ++mt) ixv[0][mt] = cidxT[ibase + (mt << 4)];
#pragma unroll
    for (int mt = 0; mt < 4; ++mt) ixv[1][mt] = cidxT[NROWS + ibase + (mt << 4)];
    CFENCE();
#pragma unroll
    for (int k = 0; k < 9; ++k)
#pragma unroll
        for (int i = 0; i < 2; ++i)
            GLDS16(wtb + (k << 13) + (((i << 5) + srow) << 7) + (cg << 4),
                   &Bw[k][(i << 12) + ldsl]);
    CFENCE();
    asm volatile("s_waitcnt vmcnt(0)" ::: "memory");  // B + idx retired
    __builtin_amdgcn_s_barrier();                     // B visible to all
    CFENCE();

    // ---- A[0] into registers ----
    bf16x8_t areg[2][4][2];
#pragma unroll
    for (int mt = 0; mt < 4; ++mt) {
        unsigned vo = ((unsigned)ixv[0][mt] << 7) + qofs;
#pragma unroll
        for (int ks = 0; ks < 2; ++ks)
            areg[0][mt][ks] = *(const bf16x8_t*)(srcb + vo + (ks << 6));
    }
    CFENCE();

    // ---- r1 k-loop: issue idx[k+2], A[k+1]; compute A[k]. No barriers. ----
#pragma unroll
    for (int k = 0; k < 9; ++k) {
        if (k < 7) {
#pragma unroll
            for (int mt = 0; mt < 4; ++mt)
                ixv[k & 1][mt] = cidxT[(k + 2) * NROWS + ibase + (mt << 4)];
        }
        if (k < 8) {
#pragma unroll
            for (int mt = 0; mt < 4; ++mt) {
                unsigned vo = ((unsigned)ixv[(k + 1) & 1][mt] << 7) + qofs;
#pragma unroll
                for (int ks = 0; ks < 2; ++ks)
                    areg[(k + 1) & 1][mt][ks] =
                        *(const bf16x8_t*)(srcb + vo + (ks << 6));
            }
        }
        CFENCE();
        bf16x8_t bq[4][2];
#pragma unroll
        for (int ks = 0; ks < 2; ++ks) {
            const int slot = ((quad | (ks << 2)) ^ sxor) << 4;
#pragma unroll
            for (int nt = 0; nt < 4; ++nt)
                bq[nt][ks] = *(const bf16x8_t*)
                    &Bw[k][(((nt << 4) + l15) << 7) + slot];
        }
        __builtin_amdgcn_s_setprio(1);
#pragma unroll
        for (int ks = 0; ks < 2; ++ks)
#pragma unroll
            for (int mt = 0; mt < 4; ++mt)
#pragma unroll
                for (int nt = 0; nt < 4; ++nt)
                    acc[mt][nt] = __builtin_amdgcn_mfma_f32_16x16x32_bf16(
                        areg[k & 1][mt][ks], bq[nt][ks], acc[mt][nt], 0, 0, 0);
        __builtin_amdgcn_s_setprio(0);
        CFENCE();
    }

    // ---- block-local stats reduction (red aliases Bw; k-loop done) ----
    float* red = (float*)Bw;
    float* sc  = red + 128;
    float* sh  = red + 192;
    __syncthreads();
    if (tid < 128) red[tid] = 0.f;
    __syncthreads();
#pragma unroll
    for (int nt = 0; nt < 4; ++nt) {
        float s = 0.f, q = 0.f;
#pragma unroll
        for (int mt = 0; mt < 4; ++mt)
#pragma unroll
            for (int r = 0; r < 4; ++r) { float v = acc[mt][nt][r]; s += v; q += v * v; }
        s += __shfl_xor(s, 16); s += __shfl_xor(s, 32);
        q += __shfl_xor(q, 16); q += __shfl_xor(q, 32);
        if (lane < 16) {
            atomicAdd(&red[(nt << 4) + lane], s);
            atomicAdd(&red[64 + (nt << 4) + lane], q);
        }
    }
    __syncthreads();
    if (tid < 128) atomicAdd(&stat[tid], red[tid]);
    __threadfence();                       // own atomics visible device-wide
    __syncthreads();

    // ---- grid-wide spin barrier (all 512 blocks co-resident) ----
    int* cnt = (int*)(stat + 128);
    if (tid == 0) {
        __hip_atomic_fetch_add(cnt, 1, __ATOMIC_ACQ_REL, __HIP_MEMORY_SCOPE_AGENT);
        int it = 0;
        while (__hip_atomic_load(cnt, __ATOMIC_ACQUIRE, __HIP_MEMORY_SCOPE_AGENT)
                   < NBLK && it < (1 << 20)) {
            __builtin_amdgcn_s_sleep(2);
            ++it;
        }
    }
    __syncthreads();
    __threadfence();                       // refresh caches before stat reads

    // ---- finalize BN scale/shift (atomic loads bypass stale caches) ----
    if (tid < 64) {
        float sm = __hip_atomic_load(&stat[tid],      __ATOMIC_ACQUIRE,
                                     __HIP_MEMORY_SCOPE_AGENT);
        float sq = __hip_atomic_load(&stat[64 + tid], __ATOMIC_ACQUIRE,
                                     __HIP_MEMORY_SCOPE_AGENT);
        float m = sm * (1.f / NROWS);
        float v = sq * (1.f / NROWS) - m * m;
        float s = gamma[tid] * rsqrtf(v + EPSBN);
        sc[tid] = s;
        sh[tid] = beta[tid] - m * s;
    }
    __syncthreads();

    // ---- apply + store (D layout: row = quad*4+reg, col = lane&15) ----
#pragma unroll
    for (int mt = 0; mt < 4; ++mt) {
        int rowb = row0 + (wv << 6) + (mt << 4) + (quad << 2);
#pragma unroll
        for (int nt = 0; nt < 4; ++nt) {
            int col = (nt << 4) + l15;
            float scv = sc[col], shv = sh[col];
#pragma unroll
            for (int r = 0; r < 4; ++r) {
                size_t off = ((size_t)(rowb + r) << 6) + col;
                float v = acc[mt][nt][r] * scv + shv;
                if (mode == 1 || mode == 3)      v += (float)residh[off];
                else if (mode == 2)              v += residf[off];
                v = leaky_f(v);
                if (mode == 3) dout[off] = v;
                else           dst[off]  = (__bf16)v;
            }
        }
    }
}

// once-per-call prep: features->bf16 mirror, weights->transposed bf16, zero
// stats (8 stages x 256 incl. spin counters), premasked transposed indices
// cidxT[k][n] (masked-out -> NROWS), zero sentinel rows. Mask encoding
// detect: center (k=4) always True -> raw byte 13 nonzero iff byte-encoded.
__global__ __launch_bounds__(256) void prep_kernel(
    const float* __restrict__ feat, const float* __restrict__ w1,
    const float* __restrict__ w2, const int* __restrict__ nidx,
    const unsigned char* __restrict__ mraw,
    __bf16* __restrict__ fh, __bf16* __restrict__ yh,
    __bf16* __restrict__ wtp, int* __restrict__ cidxT,
    float* __restrict__ stats)
{
    size_t t = ((size_t)blockIdx.x << 8) | threadIdx.x;
    if (t < 2048) stats[t] = 0.f;
    if (t < 64) {   // zero sentinel rows
        fh[(size_t)NROWS * 64 + t] = (__bf16)0.f;
        yh[(size_t)NROWS * 64 + t] = (__bf16)0.f;
    }
    if (t < 1048576) {  // features: 8 floats -> 8 bf16 per thread
        size_t i = t << 3;
        float4 a = *(const float4*)(feat + i);
        float4 b = *(const float4*)(feat + i + 4);
        bf16x8_t h;
        h[0] = (__bf16)a.x; h[1] = (__bf16)a.y; h[2] = (__bf16)a.z; h[3] = (__bf16)a.w;
        h[4] = (__bf16)b.x; h[5] = (__bf16)b.y; h[6] = (__bf16)b.z; h[7] = (__bf16)b.w;
        *(bf16x8_t*)(fh + i) = h;
    }
    if (t < 294912) {   // wtp[cv][b][k][d][c] = w[b][k][c][d]
        int o = (int)t;
        int c = o & 63, d = (o >> 6) & 63;
        int kk = o >> 12;              // 0..71
        int k = kk % 9, bb = (kk / 9) & 3, cv = kk / 36;
        const float* w = cv ? w2 : w1;
        float v = w[((size_t)((bb * 9 + k) * 64 + c) << 6) + d];
        wtp[o] = (__bf16)v;
    }
    if (t < NROWS) {    // cidxT: one thread per row n, 9 entries
        int n = (int)t;
        bool benc = (mraw[13] != 0);
        const unsigned int* mw = (const unsigned int*)mraw;
#pragma unroll
        for (int j = 0; j < 9; ++j) {
            int e = n * 9 + j;
            bool m = benc ? (mraw[e] != 0) : (mw[e] != 0u);
            cidxT[j * NROWS + n] = m ? nidx[e] : NROWS;
        }
    }
}

extern "C" void kernel_launch(void* const* d_in, const int* in_sizes, int n_in,
                              void* d_out, int out_size, void* d_ws, size_t ws_size,
                              hipStream_t stream) {
    const float* feat = (const float*)d_in[0];
    const int* nidx = (const int*)d_in[1];
    const unsigned char* mraw = (const unsigned char*)d_in[2];
    const float* w1 = (const float*)d_in[3];
    const float* g1 = (const float*)d_in[4];
    const float* b1 = (const float*)d_in[5];
    const float* w2 = (const float*)d_in[6];
    const float* g2 = (const float*)d_in[7];
    const float* b2 = (const float*)d_in[8];
    float* out = (float*)d_out;

    char* ws = (char*)d_ws;
    __bf16* xh    = (__bf16*)ws;                       // (N+1)x64 bf16 residual
    __bf16* yh    = (__bf16*)(ws + 17825792);          // (N+1)x64 bf16 conv1 out
    __bf16* wtp   = (__bf16*)(ws + 53477376);          // 0.59 MB transposed weights
    float*  stats = (float*)(ws + 54525952);           // 8 stages x 256 floats
    int*    cidxT = (int*)(ws + 54591488);             // 4.72 MB premasked idx^T

    prep_kernel<<<4096, 256, 0, stream>>>(feat, w1, w2, nidx, mraw,
                                          xh, yh, wtp, cidxT, stats);

    for (int b = 0; b < 4; ++b) {
        // conv1 + bn1 + leaky -> yh
        conv_kernel<<<NBLK, 256, 0, stream>>>(
            xh, cidxT, wtp + (size_t)b * 9 * 4096, yh,
            stats + (size_t)(2 * b) * 256, g1 + b * 64, b1 + b * 64,
            nullptr, nullptr, nullptr, 0);
        // conv2 + bn2 + residual + leaky -> xh (or out on final block)
        int mode = (b == 3) ? 3 : ((b == 0) ? 2 : 1);
        conv_kernel<<<NBLK, 256, 0, stream>>>(
            yh, cidxT, wtp + (size_t)(4 + b) * 9 * 4096, xh,
            stats + (size_t)(2 * b + 1) * 256, g2 + b * 64, b2 + b * 64,
            (b == 0) ? nullptr : xh, (b == 0) ? feat : nullptr,
            (b == 3) ? out : nullptr, mode);
    }
}

// Round 6
// 659.592 us; speedup vs baseline: 1.9389x; 1.9389x over previous
//
#include <hip/hip_runtime.h>
#include <hip/hip_bf16.h>
#include <stdint.h>

#define NROWS 131072
#define EPSBN 1e-5f
#define LEAKK 0.33f
#define NBLK  512            // 2 blocks/CU (72KB LDS): co-resident
#define NCOPY 8              // scattered stat copies (r5 lesson: 512 blocks
                             // atomicAdd-ing the SAME 128 floats + spin
                             // barrier = ~120us exposed RMW serialization)
#define STATSTRIDE 1088      // per-stage floats: 8*128 copies + cnt

typedef __bf16 bf16x8_t __attribute__((ext_vector_type(8)));
typedef float  f32x4_t  __attribute__((ext_vector_type(4)));

__device__ __forceinline__ float leaky_f(float x) { return fmaxf(x, LEAKK * x); }

#define GLDS16(g, l)                                                          \
    __builtin_amdgcn_global_load_lds(                                         \
        (const __attribute__((address_space(1))) void*)(g),                   \
        (__attribute__((address_space(3))) void*)(l), 16, 0, 0)

#define CFENCE() asm volatile("" ::: "memory")

// Fused gather-GEMM conv + BN(+leaky)(+residual), grid-wide spin sync.
// Conv body = r1's proven depth-1 reg-gather loop. Epilogue protocol v2:
// scatter-add into 8 stat copies (64 colliders/address, ~1us), release
// arrive-counter, acquire poll, relaxed-atomic gather of the 8 copies.
// Residual prefetched before the poll (HBM latency hides under spin).
// mode: 0 = y=leaky(bn(acc))          -> dst bf16   (conv1)
//       1 = y=leaky(bn(acc)+residh)   -> dst bf16   (conv2, b=1,2; dst==residh)
//       2 = y=leaky(bn(acc)+residf)   -> dst bf16   (conv2, b=0, fp32 resid)
//       3 = y=leaky(bn(acc)+residh)   -> dout fp32  (conv2, b=3, final)
__global__ __launch_bounds__(256, 2) void conv_kernel(
    const __bf16* __restrict__ src,      // (NROWS+1) x 64, row NROWS = zeros
    const int* __restrict__ cidxT,       // [9][NROWS] premasked (masked->NROWS)
    const __bf16* __restrict__ wt,       // [9][64 d][64 c]
    __bf16* dst,                         // no restrict: may alias residh
    float* __restrict__ stat,            // NCOPY*128 copies + cnt at [1024]
    const float* __restrict__ gamma, const float* __restrict__ beta,
    const __bf16* residh, const float* residf,
    float* dout, int mode)
{
    __shared__ char Bw[9][8192];         // 72KB

    const int tid  = threadIdx.x;
    const int lane = tid & 63;
    const int wv   = tid >> 6;                 // 0..3
    const int quad = lane >> 4;
    const int l15  = lane & 15;
    const int row0 = blockIdx.x << 8;          // 256 rows/block
    const int srow = tid >> 3;                 // staging row 0..31
    const int cg   = (tid & 7) ^ (srow & 7);   // swizzled global chunk
    const int ldsl = (tid & 192) << 4;         // wave-uniform lds base
    const int sxor = l15 & 7;

    const char* srcb = (const char*)src;
    const char* wtb  = (const char*)wt;

    f32x4_t acc[4][4];
#pragma unroll
    for (int mt = 0; mt < 4; ++mt)
#pragma unroll
        for (int nt = 0; nt < 4; ++nt)
            acc[mt][nt] = (f32x4_t){0.f, 0.f, 0.f, 0.f};

    const int ibase = row0 + (wv << 6) + l15;  // wave row, + mt*16 per mt
    const unsigned qofs = (unsigned)(quad << 4);

    // ---- prologue: idx k=0,1 then all 9 B tiles ----
    int ixv[2][4];
#pragma unroll
    for (int mt = 0; mt < 4; ++mt) ixv[0][mt] = cidxT[ibase + (mt << 4)];
#pragma unroll
    for (int mt = 0; mt < 4; ++mt) ixv[1][mt] = cidxT[NROWS + ibase + (mt << 4)];
    CFENCE();
#pragma unroll
    for (int k = 0; k < 9; ++k)
#pragma unroll
        for (int i = 0; i < 2; ++i)
            GLDS16(wtb + (k << 13) + (((i << 5) + srow) << 7) + (cg << 4),
                   &Bw[k][(i << 12) + ldsl]);
    CFENCE();
    asm volatile("s_waitcnt vmcnt(0)" ::: "memory");  // B + idx retired
    __builtin_amdgcn_s_barrier();                     // B visible to all
    CFENCE();

    // ---- A[0] into registers ----
    bf16x8_t areg[2][4][2];
#pragma unroll
    for (int mt = 0; mt < 4; ++mt) {
        unsigned vo = ((unsigned)ixv[0][mt] << 7) + qofs;
#pragma unroll
        for (int ks = 0; ks < 2; ++ks)
            areg[0][mt][ks] = *(const bf16x8_t*)(srcb + vo + (ks << 6));
    }
    CFENCE();

    // ---- k-loop: issue idx[k+2], A[k+1]; compute A[k]. No barriers. ----
#pragma unroll
    for (int k = 0; k < 9; ++k) {
        if (k < 7) {
#pragma unroll
            for (int mt = 0; mt < 4; ++mt)
                ixv[k & 1][mt] = cidxT[(k + 2) * NROWS + ibase + (mt << 4)];
        }
        if (k < 8) {
#pragma unroll
            for (int mt = 0; mt < 4; ++mt) {
                unsigned vo = ((unsigned)ixv[(k + 1) & 1][mt] << 7) + qofs;
#pragma unroll
                for (int ks = 0; ks < 2; ++ks)
                    areg[(k + 1) & 1][mt][ks] =
                        *(const bf16x8_t*)(srcb + vo + (ks << 6));
            }
        }
        CFENCE();
        bf16x8_t bq[4][2];
#pragma unroll
        for (int ks = 0; ks < 2; ++ks) {
            const int slot = ((quad | (ks << 2)) ^ sxor) << 4;
#pragma unroll
            for (int nt = 0; nt < 4; ++nt)
                bq[nt][ks] = *(const bf16x8_t*)
                    &Bw[k][(((nt << 4) + l15) << 7) + slot];
        }
        __builtin_amdgcn_s_setprio(1);
#pragma unroll
        for (int ks = 0; ks < 2; ++ks)
#pragma unroll
            for (int mt = 0; mt < 4; ++mt)
#pragma unroll
                for (int nt = 0; nt < 4; ++nt)
                    acc[mt][nt] = __builtin_amdgcn_mfma_f32_16x16x32_bf16(
                        areg[k & 1][mt][ks], bq[nt][ks], acc[mt][nt], 0, 0, 0);
        __builtin_amdgcn_s_setprio(0);
        CFENCE();
    }

    // ---- residual prefetch: issue now, consumed after the grid barrier ----
    float rv[4][4][4];
    if (mode != 0) {
#pragma unroll
        for (int mt = 0; mt < 4; ++mt) {
            int rowb = row0 + (wv << 6) + (mt << 4) + (quad << 2);
#pragma unroll
            for (int nt = 0; nt < 4; ++nt) {
                int col = (nt << 4) + l15;
#pragma unroll
                for (int r = 0; r < 4; ++r) {
                    size_t off = ((size_t)(rowb + r) << 6) + col;
                    rv[mt][nt][r] = (mode == 2) ? residf[off]
                                                : (float)residh[off];
                }
            }
        }
    }
    CFENCE();

    // ---- block-local stats reduction (red aliases Bw; k-loop done) ----
    float* red = (float*)Bw;
    float* sc  = red + 128;
    float* sh  = red + 192;
    __syncthreads();
    if (tid < 128) red[tid] = 0.f;
    __syncthreads();
#pragma unroll
    for (int nt = 0; nt < 4; ++nt) {
        float s = 0.f, q = 0.f;
#pragma unroll
        for (int mt = 0; mt < 4; ++mt)
#pragma unroll
            for (int r = 0; r < 4; ++r) { float v = acc[mt][nt][r]; s += v; q += v * v; }
        s += __shfl_xor(s, 16); s += __shfl_xor(s, 32);
        q += __shfl_xor(q, 16); q += __shfl_xor(q, 32);
        if (lane < 16) {
            atomicAdd(&red[(nt << 4) + lane], s);
            atomicAdd(&red[64 + (nt << 4) + lane], q);
        }
    }
    __syncthreads();

    // ---- scatter-add into copy (bid&7): 64 colliders/address ----
    float* mycopy = stat + ((blockIdx.x & (NCOPY - 1)) << 7);
    if (tid < 128)
        __hip_atomic_fetch_add(&mycopy[tid], red[tid],
                               __ATOMIC_RELAXED, __HIP_MEMORY_SCOPE_AGENT);
    __syncthreads();                       // all adds of this block issued+done

    // ---- arrive (release) + poll (acquire) ----
    int* cnt = (int*)(stat + 1024);
    if (tid == 0) {
        __hip_atomic_fetch_add(cnt, 1, __ATOMIC_ACQ_REL, __HIP_MEMORY_SCOPE_AGENT);
        int it = 0;
        while (__hip_atomic_load(cnt, __ATOMIC_ACQUIRE, __HIP_MEMORY_SCOPE_AGENT)
                   < NBLK && it < (1 << 18)) {
            __builtin_amdgcn_s_sleep(8);
            ++it;
        }
    }
    __syncthreads();

    // ---- gather the 8 copies (coherent relaxed atomic loads) ----
    if (tid < 128) {
        float s = 0.f;
#pragma unroll
        for (int c = 0; c < NCOPY; ++c)
            s += __hip_atomic_load(stat + (c << 7) + tid,
                                   __ATOMIC_RELAXED, __HIP_MEMORY_SCOPE_AGENT);
        red[tid] = s;
    }
    __syncthreads();
    if (tid < 64) {
        float m = red[tid] * (1.f / NROWS);
        float v = red[64 + tid] * (1.f / NROWS) - m * m;
        float s = gamma[tid] * rsqrtf(v + EPSBN);
        sc[tid] = s;
        sh[tid] = beta[tid] - m * s;
    }
    __syncthreads();

    // ---- apply + store (D layout: row = quad*4+reg, col = lane&15) ----
#pragma unroll
    for (int mt = 0; mt < 4; ++mt) {
        int rowb = row0 + (wv << 6) + (mt << 4) + (quad << 2);
#pragma unroll
        for (int nt = 0; nt < 4; ++nt) {
            int col = (nt << 4) + l15;
            float scv = sc[col], shv = sh[col];
#pragma unroll
            for (int r = 0; r < 4; ++r) {
                size_t off = ((size_t)(rowb + r) << 6) + col;
                float v = acc[mt][nt][r] * scv + shv;
                if (mode != 0) v += rv[mt][nt][r];
                v = leaky_f(v);
                if (mode == 3) dout[off] = v;
                else           dst[off]  = (__bf16)v;
            }
        }
    }
}

// once-per-call prep: features->bf16 mirror, weights->transposed bf16, zero
// stats (8 stages x STATSTRIDE incl. copies + counters), premasked transposed
// indices cidxT[k][n] (masked-out -> NROWS), zero sentinel rows. Mask
// encoding detect: center (k=4) always True -> byte 13 nonzero iff byte-enc.
__global__ __launch_bounds__(256) void prep_kernel(
    const float* __restrict__ feat, const float* __restrict__ w1,
    const float* __restrict__ w2, const int* __restrict__ nidx,
    const unsigned char* __restrict__ mraw,
    __bf16* __restrict__ fh, __bf16* __restrict__ yh,
    __bf16* __restrict__ wtp, int* __restrict__ cidxT,
    float* __restrict__ stats)
{
    size_t t = ((size_t)blockIdx.x << 8) | threadIdx.x;
    if (t < 8 * STATSTRIDE) stats[t] = 0.f;
    if (t < 64) {   // zero sentinel rows
        fh[(size_t)NROWS * 64 + t] = (__bf16)0.f;
        yh[(size_t)NROWS * 64 + t] = (__bf16)0.f;
    }
    if (t < 1048576) {  // features: 8 floats -> 8 bf16 per thread
        size_t i = t << 3;
        float4 a = *(const float4*)(feat + i);
        float4 b = *(const float4*)(feat + i + 4);
        bf16x8_t h;
        h[0] = (__bf16)a.x; h[1] = (__bf16)a.y; h[2] = (__bf16)a.z; h[3] = (__bf16)a.w;
        h[4] = (__bf16)b.x; h[5] = (__bf16)b.y; h[6] = (__bf16)b.z; h[7] = (__bf16)b.w;
        *(bf16x8_t*)(fh + i) = h;
    }
    if (t < 294912) {   // wtp[cv][b][k][d][c] = w[b][k][c][d]
        int o = (int)t;
        int c = o & 63, d = (o >> 6) & 63;
        int kk = o >> 12;              // 0..71
        int k = kk % 9, bb = (kk / 9) & 3, cv = kk / 36;
        const float* w = cv ? w2 : w1;
        float v = w[((size_t)((bb * 9 + k) * 64 + c) << 6) + d];
        wtp[o] = (__bf16)v;
    }
    if (t < NROWS) {    // cidxT: one thread per row n, 9 entries
        int n = (int)t;
        bool benc = (mraw[13] != 0);
        const unsigned int* mw = (const unsigned int*)mraw;
#pragma unroll
        for (int j = 0; j < 9; ++j) {
            int e = n * 9 + j;
            bool m = benc ? (mraw[e] != 0) : (mw[e] != 0u);
            cidxT[j * NROWS + n] = m ? nidx[e] : NROWS;
        }
    }
}

extern "C" void kernel_launch(void* const* d_in, const int* in_sizes, int n_in,
                              void* d_out, int out_size, void* d_ws, size_t ws_size,
                              hipStream_t stream) {
    const float* feat = (const float*)d_in[0];
    const int* nidx = (const int*)d_in[1];
    const unsigned char* mraw = (const unsigned char*)d_in[2];
    const float* w1 = (const float*)d_in[3];
    const float* g1 = (const float*)d_in[4];
    const float* b1 = (const float*)d_in[5];
    const float* w2 = (const float*)d_in[6];
    const float* g2 = (const float*)d_in[7];
    const float* b2 = (const float*)d_in[8];
    float* out = (float*)d_out;

    char* ws = (char*)d_ws;
    __bf16* xh    = (__bf16*)ws;                       // (N+1)x64 bf16 residual
    __bf16* yh    = (__bf16*)(ws + 17825792);          // (N+1)x64 bf16 conv1 out
    __bf16* wtp   = (__bf16*)(ws + 53477376);          // 0.59 MB transposed weights
    float*  stats = (float*)(ws + 54525952);           // 8 stages x 1088 floats
    int*    cidxT = (int*)(ws + 54591488);             // 4.72 MB premasked idx^T

    prep_kernel<<<4096, 256, 0, stream>>>(feat, w1, w2, nidx, mraw,
                                          xh, yh, wtp, cidxT, stats);

    for (int b = 0; b < 4; ++b) {
        // conv1 + bn1 + leaky -> yh
        conv_kernel<<<NBLK, 256, 0, stream>>>(
            xh, cidxT, wtp + (size_t)b * 9 * 4096, yh,
            stats + (size_t)(2 * b) * STATSTRIDE, g1 + b * 64, b1 + b * 64,
            nullptr, nullptr, nullptr, 0);
        // conv2 + bn2 + residual + leaky -> xh (or out on final block)
        int mode = (b == 3) ? 3 : ((b == 0) ? 2 : 1);
        conv_kernel<<<NBLK, 256, 0, stream>>>(
            yh, cidxT, wtp + (size_t)(4 + b) * 9 * 4096, xh,
            stats + (size_t)(2 * b + 1) * STATSTRIDE, g2 + b * 64, b2 + b * 64,
            (b == 0) ? nullptr : xh, (b == 0) ? feat : nullptr,
            (b == 3) ? out : nullptr, mode);
    }
}